// Round 8
// baseline (171.829 us; speedup 1.0000x reference)
//
#include <hip/hip_runtime.h>
#include <hip/hip_bf16.h>

// Problem constants
#define TT   20
#define TS   19          // T-1 steps
#define BB   16
#define HH   128
#define WW   128
#define CINN 2
#define CHN  64
#define NOUT 10
#define BETA 0.9f
#define INVB (1.0f / BETA)

#define NCHUNK 5                              // ceil(19/4) byte-packed t-chunks
#define NPB    128                            // partial blocks per batch
#define SR_IDX (BB*NOUT + TS*BB*NOUT)         // scalar spike-rate slot in out

// ---- packed-flow frame geometry ----
// frame[plane][y][pp]: plane in {hi,lo}, y in 0..128 (row 128 = zeros),
// pp = px+1 in 0..131 (pp 0,129,130,131 zeroed -> borderless halo reads).
#define PPD      132
#define ROWB     (PPD*4)                      // 528 B row stride
#define PROWS    129
#define PLANE_B  (PROWS*ROWB)                 // 68,112 B
#define FRAME_B  (2*PLANE_B)                  // 136,224 B
#define FLOW_B   ((size_t)BB*TS*FRAME_B)      // 41,412,096 B
#define SLACK_B  528                          // zeroed tail (x4-load overrun)
#define CNT_OFF4 ((size_t)(FLOW_B + SLACK_B) / 4)
#define CNT_B    ((size_t)BB*NCHUNK*NPB*CHN*4)
#define WS_NEED  (FLOW_B + SLACK_B + CNT_B)   // ~44.0 MB

// ---- round-5 fallback geometry ----
#define LROW  20                              // dwords per staged row (18 + 2 pad)

typedef __attribute__((ext_vector_type(8))) short short8;
typedef __attribute__((ext_vector_type(4))) float float4v;
typedef __attribute__((ext_vector_type(16))) float floatv16;
typedef __attribute__((ext_vector_type(4))) int   int4v;
typedef unsigned uint4v_t __attribute__((ext_vector_type(4)));
typedef uint4v_t __attribute__((aligned(4))) uint4vu;   // 4B-aligned vector load
typedef unsigned uint2v_t __attribute__((ext_vector_type(2)));
typedef uint2v_t __attribute__((aligned(4))) uint2vu;   // 4B-aligned vector store

// round-to-nearest-even fp32 -> bf16 bits
__device__ __forceinline__ unsigned rne16(float f) {
    unsigned u = __float_as_uint(f);
    return (u + 0x7fffu + ((u >> 16) & 1u)) >> 16;
}
__device__ __forceinline__ float b2f(unsigned us) { return __uint_as_float(us << 16); }
__device__ __forceinline__ unsigned rndb(float f) {          // rounded bits, un-shifted
    unsigned u = __float_as_uint(f);
    return u + 0x7fffu + ((u >> 16) & 1u);
}
// hi/lo bf16 split of a pixel-pair, packed via v_perm.
__device__ __forceinline__ void pack2(float d0, float d1, unsigned &hi, unsigned &lo) {
    unsigned r0 = rndb(d0), r1 = rndb(d1);
    hi = __builtin_amdgcn_perm(r1, r0, 0x07060302u);
    float e0 = d0 - __uint_as_float(r0 & 0xffff0000u);
    float e1 = d1 - __uint_as_float(r1 & 0xffff0000u);
    lo = __builtin_amdgcn_perm(rndb(e1), rndb(e0), 0x07060302u);
}

// ---------------------------------------------------------------------------
// flow_pack: t-looped READ-ONCE producer (x read exactly once; ~83 MB total
// traffic). One-ahead prefetch; paired pixels -> 8B stores; borders zeroed
// in-loop. Bit-identical ct chain.
// ---------------------------------------------------------------------------
__global__ __launch_bounds__(256) void flow_pack(const float* __restrict__ x,
                                                 unsigned* __restrict__ wsf) {
    const int bx  = blockIdx.x;               // 0..31 : row-group of 4
    const int b   = blockIdx.y;               // batch
    const int tid = threadIdx.x;
    const int row = (bx << 2) + (tid >> 6);   // 64 threads per row
    const int p0  = (tid & 63) << 1;          // 2 px per thread

    const int TSTR = BB * HH * WW / 2;        // float4s per time slice
    const float4* xr = (const float4*)x + ((b * HH + row) * WW + p0) / 2;
    char* fb = (char*)wsf + (size_t)b * TS * FRAME_B;
    const unsigned off = (unsigned)(row * PPD + p0 + 1) * 4u;

    float4 cur = xr[0];
    float4 nxt = xr[TSTR];
    float ct = 1.f;
#pragma unroll 1
    for (int t = 0; t < TS; ++t) {
        float4 fut = nxt;
        if (t + 2 <= TS) fut = xr[(t + 2) * TSTR];
        float d0 = (nxt.x - cur.x) * ct, d1 = (nxt.y - cur.y) * ct;
        float d2 = (nxt.z - cur.z) * ct, d3 = (nxt.w - cur.w) * ct;
        unsigned h0, l0, h1, l1;
        pack2(d0, d1, h0, l0);
        pack2(d2, d3, h1, l1);
        uint2v_t hv = {h0, h1}, lv = {l0, l1};
        *(uint2vu*)(fb + off) = hv;
        *(uint2vu*)(fb + PLANE_B + off) = lv;
        if ((tid & 63) < 8) {
            int c  = tid & 7;
            int pl = c >> 2;
            int pp = (c & 3) == 0 ? 0 : 128 + (c & 3);
            *(unsigned*)(fb + pl * PLANE_B + (row * PPD + pp) * 4) = 0u;
        }
        if (bx == 0) {
            for (int d = tid; d < 2 * PPD; d += 256) {
                int pl = d >= PPD, pp = d - pl * PPD;
                *(unsigned*)(fb + pl * PLANE_B + (128 * PPD + pp) * 4) = 0u;
            }
        }
        cur = nxt; nxt = fut;
        fb += FRAME_B; ct *= INVB;
    }
    if (bx == 0 && b == 0 && tid < PPD)
        *((unsigned*)((char*)wsf + FLOW_B) + tid) = 0u;
}

// ---------------------------------------------------------------------------
// lif_fast v2: 32x32x16 MFMA (the faster pipe, half the MFMA instructions).
// Wave tile = 16px x 2 image rows, flattened to the 32-row A operand:
//   A row p = lane&31 -> (rimg = r0 + (p>>4), px = x0 + (p&15))
//   A k = 8*(lane>>5) + e ; taps k = q*8 + j with q = 2m + h (m = MFMA idx,
//   h = lane>>5).  quad0 load = row rimg-1+h, quad1 = row rimg+1 (h=1 half
//   dead x B==0).  Same 4 dwordx4 loads/step as before.
// C/D: col = lane&31 = channel-in-tile (tile t -> ch = t*32+col); each lane
// holds 16 of 32 rows, partner lane (^32) the rest -> count = 1 shfl_xor.
// W-space LIF via MFMA C-operand; byte-packed deferred counts; zero global
// atomics; (256,4): ~120 total regs -> 4 blocks/CU.
// ---------------------------------------------------------------------------
__global__ __launch_bounds__(256, 4) void lif_fast(const char* __restrict__ flow,
                                                   const float* __restrict__ w_conv,
                                                   const float* __restrict__ b_conv,
                                                   int* __restrict__ cw,
                                                   float* __restrict__ out) {
    __shared__ int lds_cnt[NCHUNK][CHN];          // 1280 B

    const int tid  = threadIdx.x;
    const int lane = tid & 63;
    const int wv   = __builtin_amdgcn_readfirstlane(tid >> 6);
    const int bx   = blockIdx.x;                 // 0..1 : pixel half
    const int r0   = blockIdx.y << 1;            // first of 2 output rows
    const int bz   = blockIdx.z;                 // batch
    const int h    = lane >> 5;                  // k-half / row-half
    const int colB = lane & 31;                  // channel within tile
    const int x0   = (bx << 6) + (wv << 4);

    if (bx == 0 && blockIdx.y == 0 && bz == 0) {
        if (tid < BB * NOUT) out[tid] = 0.f;
        else if (tid == BB * NOUT) out[SR_IDX] = 0.f;
    }
    if (tid < NCHUNK * CHN - 256) ((int*)lds_cnt)[256 + tid] = 0;
    ((int*)lds_cnt)[tid] = 0;
    __syncthreads();

    // per-lane invariant frame offsets (y remapped to zero row at borders)
    const int rimg = r0 + ((lane >> 4) & 1);
    const int xpx  = x0 + (lane & 15);
    const int ya   = rimg - 1 + h;               // quad0 row (ky = h)
    const int yb   = rimg + 1;                   // quad1 row (ky = 2; h=1 dead)
    const int yam  = ((unsigned)ya < (unsigned)HH) ? ya : 128;
    const int ybm  = ((unsigned)yb < (unsigned)HH) ? yb : 128;
    const unsigned offQ0 = (unsigned)(yam * ROWB + xpx * 4);
    const unsigned offQ1 = (unsigned)(ybm * ROWB + xpx * 4);

    // ---- B fragments: [tile][m], k = 8h+e -> tap q = 2m+h, j = e (<6)
    short8 Bh[2][2], Bl[2][2];
#pragma unroll
    for (int t = 0; t < 2; ++t) {
#pragma unroll
        for (int m = 0; m < 2; ++m) {
            const int q = 2 * m + h;
            int hi_i[4] = {0, 0, 0, 0}, lo_i[4] = {0, 0, 0, 0};
            if (q < 3) {
#pragma unroll
                for (int e = 0; e < 6; ++e) {
                    float w = w_conv[((q * 3 + (e >> 1)) * 2 + (e & 1)) * CHN + t * 32 + colB];
                    unsigned hs = rne16(w);
                    unsigned ls = rne16(w - b2f(hs));
                    hi_i[e >> 1] |= (int)(hs << (16 * (e & 1)));
                    lo_i[e >> 1] |= (int)(ls << (16 * (e & 1)));
                }
            }
            int4v hv = {hi_i[0], hi_i[1], hi_i[2], hi_i[3]};
            int4v lv = {lo_i[0], lo_i[1], lo_i[2], lo_i[3]};
            Bh[t][m] = __builtin_bit_cast(short8, hv);
            Bl[t][m] = __builtin_bit_cast(short8, lv);
        }
    }

    const float nb0 = -b_conv[colB];
    const float nb1 = -b_conv[32 + colB];

    floatv16 W0 = {0.f,0.f,0.f,0.f,0.f,0.f,0.f,0.f,0.f,0.f,0.f,0.f,0.f,0.f,0.f,0.f};
    floatv16 W1 = {0.f,0.f,0.f,0.f,0.f,0.f,0.f,0.f,0.f,0.f,0.f,0.f,0.f,0.f,0.f,0.f};

    float ct = 1.0f, S = 1.0f;
    int pend = 0;
    unsigned cur = 0;

    const char* fp = flow + (size_t)bz * TS * FRAME_B;
    // prologue: frame 0 into the E set
    uint4vu eQ0h = *(const uint4vu*)(fp + offQ0);
    uint4vu eQ1h = *(const uint4vu*)(fp + offQ1);
    uint4vu eQ0l = *(const uint4vu*)(fp + PLANE_B + offQ0);
    uint4vu eQ1l = *(const uint4vu*)(fp + PLANE_B + offQ1);
    fp += FRAME_B;
    uint4vu oQ0h, oQ1h, oQ0l, oQ1l;

#define MFMA32 __builtin_amdgcn_mfma_f32_32x32x16_bf16

#define STEP(T_, CQ0H, CQ1H, CQ0L, CQ1L, NQ0H, NQ1H, NQ0L, NQ1L, DPOS, DODEF, DOFLUSH, CK, DOLOAD) do { \
    int sh_ = 0;                                                                \
    if (DODEF) sh_ = __shfl_xor(pend, 32);                                      \
    if (DOLOAD) {                                                               \
        NQ0H = *(const uint4vu*)(fp + offQ0);                                   \
        NQ1H = *(const uint4vu*)(fp + offQ1);                                   \
        NQ0L = *(const uint4vu*)(fp + PLANE_B + offQ0);                         \
        NQ1L = *(const uint4vu*)(fp + PLANE_B + offQ1);                         \
        fp += FRAME_B;                                                          \
    }                                                                           \
    float ctn = ct * INVB;                                                      \
    short8 A0h = __builtin_bit_cast(short8, CQ0H);                              \
    short8 A1h = __builtin_bit_cast(short8, CQ1H);                              \
    short8 A0l = __builtin_bit_cast(short8, CQ0L);                              \
    short8 A1l = __builtin_bit_cast(short8, CQ1L);                              \
    __builtin_amdgcn_s_setprio(1);                                              \
    W0 = MFMA32(A0h, Bh[0][0], W0, 0, 0, 0);                                    \
    W1 = MFMA32(A0h, Bh[1][0], W1, 0, 0, 0);                                    \
    W0 = MFMA32(A1h, Bh[0][1], W0, 0, 0, 0);                                    \
    W1 = MFMA32(A1h, Bh[1][1], W1, 0, 0, 0);                                    \
    W0 = MFMA32(A0l, Bh[0][0], W0, 0, 0, 0);                                    \
    W1 = MFMA32(A0l, Bh[1][0], W1, 0, 0, 0);                                    \
    W0 = MFMA32(A1l, Bh[0][1], W0, 0, 0, 0);                                    \
    W1 = MFMA32(A1l, Bh[1][1], W1, 0, 0, 0);                                    \
    W0 = MFMA32(A0h, Bl[0][0], W0, 0, 0, 0);                                    \
    W1 = MFMA32(A0h, Bl[1][0], W1, 0, 0, 0);                                    \
    W0 = MFMA32(A1h, Bl[0][1], W0, 0, 0, 0);                                    \
    W1 = MFMA32(A1h, Bl[1][1], W1, 0, 0, 0);                                    \
    __builtin_amdgcn_s_setprio(0);                                              \
    if (DODEF) {                                                                \
        unsigned tot_ = (unsigned)(pend + sh_);                                 \
        unsigned mych = (tot_ >> (h << 3)) & 255u;                              \
        cur |= mych << (8 * (DPOS));                                            \
        if (DOFLUSH) { atomicAdd(&lds_cnt[CK][lane], (int)cur); cur = 0u; }     \
    }                                                                           \
    float thr0 = fmaf(nb0, S, ct);                                              \
    float thr1 = fmaf(nb1, S, ct);                                              \
    int c0 = 0, c1 = 0;                                                         \
    _Pragma("unroll")                                                           \
    for (int r = 0; r < 16; ++r) {                                              \
        float v0 = W0[r]; bool s0 = v0 > thr0;                                  \
        W0[r] = s0 ? (v0 - ct) : v0; c0 += s0;                                  \
        float v1 = W1[r]; bool s1 = v1 > thr1;                                  \
        W1[r] = s1 ? (v1 - ct) : v1; c1 += s1;                                  \
    }                                                                           \
    pend = c0 | (c1 << 8);                                                      \
    ct = ctn; S += ctn;                                                         \
} while (0)

#pragma unroll 1
    for (int c = 0; c < 4; ++c) {                // steps 0..15
        STEP(4 * c + 0, eQ0h, eQ1h, eQ0l, eQ1l, oQ0h, oQ1h, oQ0l, oQ1l, 3, (c > 0), (c > 0), (c - 1), 1);
        STEP(4 * c + 1, oQ0h, oQ1h, oQ0l, oQ1l, eQ0h, eQ1h, eQ0l, eQ1l, 0, 1, 0, 0, 1);
        STEP(4 * c + 2, eQ0h, eQ1h, eQ0l, eQ1l, oQ0h, oQ1h, oQ0l, oQ1l, 1, 1, 0, 0, 1);
        STEP(4 * c + 3, oQ0h, oQ1h, oQ0l, oQ1l, eQ0h, eQ1h, eQ0l, eQ1l, 2, 1, 0, 0, 1);
    }
    STEP(16, eQ0h, eQ1h, eQ0l, eQ1l, oQ0h, oQ1h, oQ0l, oQ1l, 3, 1, 1, 3, 1);
    STEP(17, oQ0h, oQ1h, oQ0l, oQ1l, eQ0h, eQ1h, eQ0l, eQ1l, 0, 1, 0, 0, 1);
    STEP(18, eQ0h, eQ1h, eQ0l, eQ1l, oQ0h, oQ1h, oQ0l, oQ1l, 1, 1, 0, 0, 0);
#undef STEP
#undef MFMA32

    // flush step 18's count (byte 2) and chunk 4
    {
        int sh = __shfl_xor(pend, 32);
        unsigned mych = ((unsigned)(pend + sh) >> (h << 3)) & 255u;
        cur |= mych << 16;
        atomicAdd(&lds_cnt[4][lane], (int)cur);
    }
    __syncthreads();

    {
        const int pb = (blockIdx.y << 1) | bx;   // 0..127
        const int k0 = tid >> 6, ch = tid & 63;
        cw[((bz * NCHUNK + k0) * NPB + pb) * CHN + ch] = lds_cnt[k0][ch];
        if (tid < CHN)
            cw[((bz * NCHUNK + 4) * NPB + pb) * CHN + tid] = lds_cnt[4][tid];
    }
}

// ---------------------------------------------------------------------------
// Round-5 fallback (small-workspace path): in-loop pack + LDS staging.
// ---------------------------------------------------------------------------
__global__ __launch_bounds__(256, 4) void lif_main(const float* __restrict__ x,
                                                   const float* __restrict__ w_conv,
                                                   const float* __restrict__ b_conv,
                                                   int* __restrict__ ws,
                                                   float* __restrict__ out) {
    __shared__ unsigned lds[4][2][2][4 * LROW];
    __shared__ int lds_cnt[NCHUNK][CHN];

    const float2* xp2 = (const float2*)x;
    const int FRAME2  = BB * HH * WW;

    const int tid  = threadIdx.x;
    const int lane = tid & 63;
    const int wv   = __builtin_amdgcn_readfirstlane(tid >> 6);
    const int bx   = blockIdx.x;
    const int r0   = blockIdx.y << 1;
    const int bz   = blockIdx.z;
    const int q    = lane >> 4;
    const int col  = lane & 15;
    const int x0   = (bx << 6) + (wv << 4);
    const int qsh  = q << 3;

    if (bx == 0 && blockIdx.y == 0 && bz == 0) {
        if (tid < BB * NOUT) out[tid] = 0.f;
        else if (tid == BB * NOUT) out[SR_IDX] = 0.f;
    }
    if (tid < NCHUNK * CHN - 256) ((int*)lds_cnt)[256 + tid] = 0;
    ((int*)lds_cnt)[tid] = 0;
    __syncthreads();

    const int  row0 = lane / 18, dx0 = lane - row0 * 18;
    const int  y0s  = r0 - 1 + row0;
    const int  px0s = x0 - 1 + dx0;
    const bool val0 = ((unsigned)y0s < (unsigned)HH) && ((unsigned)px0s < (unsigned)WW);
    const int  off0 = val0 ? (y0s * WW + px0s) : 0;
    const int  ls0  = row0 * LROW + dx0;

    const bool act1 = (lane < 8);
    const int  y1s  = r0 + 2;
    const int  px1s = x0 - 1 + 10 + lane;
    const bool val1 = act1 && ((unsigned)y1s < (unsigned)HH) && ((unsigned)px1s < (unsigned)WW);
    const int  off1 = val1 ? (y1s * WW + px1s) : 0;
    const int  ls1  = 3 * LROW + 10 + lane;

    const int rq  = (q < 3) ? q : 0;
    const int rdb = rq * LROW + col;

    short8 Bh[4], Bl[4];
#pragma unroll
    for (int cg = 0; cg < 4; ++cg) {
        int hi_i[4] = {0, 0, 0, 0}, lo_i[4] = {0, 0, 0, 0};
        if (q < 3) {
#pragma unroll
            for (int j = 0; j < 6; ++j) {
                float w = w_conv[((q * 3 + (j >> 1)) * 2 + (j & 1)) * CHN + cg * 16 + col];
                unsigned hs = rne16(w);
                unsigned ls = rne16(w - b2f(hs));
                hi_i[j >> 1] |= (int)(hs << (16 * (j & 1)));
                lo_i[j >> 1] |= (int)(ls << (16 * (j & 1)));
            }
        }
        int4v hv = {hi_i[0], hi_i[1], hi_i[2], hi_i[3]};
        int4v lv = {lo_i[0], lo_i[1], lo_i[2], lo_i[3]};
        Bh[cg] = __builtin_bit_cast(short8, hv);
        Bl[cg] = __builtin_bit_cast(short8, lv);
    }

    float nb[4];
#pragma unroll
    for (int cg = 0; cg < 4; ++cg) nb[cg] = -b_conv[cg * 16 + col];

    float4v W0[4], W1[4];
#pragma unroll
    for (int cg = 0; cg < 4; ++cg) {
        W0[cg] = (float4v){0.f, 0.f, 0.f, 0.f};
        W1[cg] = (float4v){0.f, 0.f, 0.f, 0.f};
    }

    float ct = 1.0f, S = 1.0f;
    int pendA = 0, pendB = 0;
    unsigned cur = 0;

    float2 ra_0 = {0.f, 0.f}, rb_0 = {0.f, 0.f}, rc_0 = {0.f, 0.f};
    float2 ra_1 = {0.f, 0.f}, rb_1 = {0.f, 0.f}, rc_1 = {0.f, 0.f};
    const float2* xb = xp2 + bz * HH * WW;
    if (val0) { rb_0 = xb[off0]; ra_0 = xb[FRAME2 + off0]; rc_0 = xb[2 * FRAME2 + off0]; }
    if (val1) { rb_1 = xb[off1]; ra_1 = xb[FRAME2 + off1]; rc_1 = xb[2 * FRAME2 + off1]; }
    {
        unsigned* hiW = &lds[wv][0][0][0];
        unsigned* loW = &lds[wv][0][1][0];
        {
            float d0 = (ra_0.x - rb_0.x), d1 = (ra_0.y - rb_0.y);
            unsigned hw, lw; pack2(d0, d1, hw, lw);
            hiW[ls0] = hw; loW[ls0] = lw;
        }
        if (act1) {
            float d0 = (ra_1.x - rb_1.x), d1 = (ra_1.y - rb_1.y);
            unsigned hw, lw; pack2(d0, d1, hw, lw);
            hiW[ls1] = hw; loW[ls1] = lw;
        }
        rb_0 = ra_0; ra_0 = rc_0;
        rb_1 = ra_1; ra_1 = rc_1;
        if (val0) rc_0 = xb[3 * FRAME2 + off0];
        if (val1) rc_1 = xb[3 * FRAME2 + off1];
    }
    const float2* xn = xb + 4 * FRAME2;

#define STEP(T_, CURB, NXTB, DPOS, DODEF, DOFLUSH, CK, DOSTAGE, DOPREF) do {    \
    const unsigned* hiR = &lds[wv][CURB][0][0] + rdb;                           \
    const unsigned* loR = &lds[wv][CURB][1][0] + rdb;                           \
    unsigned h0 = hiR[0], h1 = hiR[1], h2 = hiR[2];                             \
    unsigned h3 = hiR[LROW], h4 = hiR[LROW + 1], h5 = hiR[LROW + 2];            \
    unsigned l0 = loR[0], l1 = loR[1], l2 = loR[2];                             \
    unsigned l3 = loR[LROW], l4 = loR[LROW + 1], l5 = loR[LROW + 2];            \
    int cp1_ = 0, sh2_ = 0;                                                     \
    if (DODEF) { cp1_ = pendA + pendB; sh2_ = __shfl_xor(cp1_, 32); }           \
    float ctn = ct * INVB;                                                      \
    if (DOSTAGE) {                                                              \
        unsigned* hiW = &lds[wv][NXTB][0][0];                                   \
        unsigned* loW = &lds[wv][NXTB][1][0];                                   \
        {                                                                       \
            float d0 = (ra_0.x - rb_0.x) * ctn;                                 \
            float d1 = (ra_0.y - rb_0.y) * ctn;                                 \
            unsigned hw, lw; pack2(d0, d1, hw, lw);                             \
            hiW[ls0] = hw; loW[ls0] = lw;                                       \
        }                                                                       \
        if (act1) {                                                             \
            float d0 = (ra_1.x - rb_1.x) * ctn;                                 \
            float d1 = (ra_1.y - rb_1.y) * ctn;                                 \
            unsigned hw, lw; pack2(d0, d1, hw, lw);                             \
            hiW[ls1] = hw; loW[ls1] = lw;                                       \
        }                                                                       \
        rb_0 = ra_0; ra_0 = rc_0;                                               \
        rb_1 = ra_1; ra_1 = rc_1;                                               \
        if (DOPREF) {                                                           \
            if (val0) rc_0 = xn[off0];                                          \
            if (val1) rc_1 = xn[off1];                                          \
            xn += FRAME2;                                                       \
        }                                                                       \
    }                                                                           \
    int4v a0h = {(int)h0, (int)h1, (int)h2, (int)h0};                           \
    int4v a0l = {(int)l0, (int)l1, (int)l2, (int)l0};                           \
    int4v a1h = {(int)h3, (int)h4, (int)h5, (int)h3};                           \
    int4v a1l = {(int)l3, (int)l4, (int)l5, (int)l3};                           \
    short8 A0h = __builtin_bit_cast(short8, a0h);                               \
    short8 A0l = __builtin_bit_cast(short8, a0l);                               \
    short8 A1h = __builtin_bit_cast(short8, a1h);                               \
    short8 A1l = __builtin_bit_cast(short8, a1l);                               \
    __builtin_amdgcn_s_setprio(1);                                              \
    _Pragma("unroll")                                                           \
    for (int cg = 0; cg < 4; ++cg) {                                            \
        W0[cg] = __builtin_amdgcn_mfma_f32_16x16x32_bf16(A0h, Bh[cg], W0[cg], 0, 0, 0); \
        W1[cg] = __builtin_amdgcn_mfma_f32_16x16x32_bf16(A1h, Bh[cg], W1[cg], 0, 0, 0); \
    }                                                                           \
    _Pragma("unroll")                                                           \
    for (int cg = 0; cg < 4; ++cg) {                                            \
        W0[cg] = __builtin_amdgcn_mfma_f32_16x16x32_bf16(A0l, Bh[cg], W0[cg], 0, 0, 0); \
        W1[cg] = __builtin_amdgcn_mfma_f32_16x16x32_bf16(A1l, Bh[cg], W1[cg], 0, 0, 0); \
    }                                                                           \
    _Pragma("unroll")                                                           \
    for (int cg = 0; cg < 4; ++cg) {                                            \
        W0[cg] = __builtin_amdgcn_mfma_f32_16x16x32_bf16(A0h, Bl[cg], W0[cg], 0, 0, 0); \
        W1[cg] = __builtin_amdgcn_mfma_f32_16x16x32_bf16(A1h, Bl[cg], W1[cg], 0, 0, 0); \
    }                                                                           \
    __builtin_amdgcn_s_setprio(0);                                              \
    if (DODEF) {                                                                \
        unsigned cnt_ = ((unsigned)(cp1_ + sh2_) >> qsh) & 255u;                \
        cur |= cnt_ << (8 * (DPOS));                                            \
        if (DOFLUSH) { atomicAdd(&lds_cnt[CK][lane], (int)cur); cur = 0u; }     \
    }                                                                           \
    int cpack = 0;                                                              \
    _Pragma("unroll")                                                           \
    for (int cg = 0; cg < 4; ++cg) {                                            \
        float thr = fmaf(nb[cg], S, ct);                                        \
        float4v w0 = W0[cg], w1 = W1[cg];                                       \
        int c = 0;                                                              \
        _Pragma("unroll")                                                       \
        for (int r = 0; r < 4; ++r) {                                           \
            float v0 = w0[r]; bool s0 = v0 > thr;                               \
            w0[r] = s0 ? (v0 - ct) : v0; c += s0;                               \
            float v1 = w1[r]; bool s1 = v1 > thr;                               \
            w1[r] = s1 ? (v1 - ct) : v1; c += s1;                               \
        }                                                                       \
        W0[cg] = w0; W1[cg] = w1;                                               \
        cpack |= c << (8 * cg);                                                 \
    }                                                                           \
    pendA = cpack;                                                              \
    pendB = __shfl_xor(cpack, 16);                                              \
    ct = ctn; S += ctn;                                                         \
} while (0)

#pragma unroll 1
    for (int c = 0; c < 4; ++c) {
        STEP(4 * c + 0, 0, 1, 3, (c > 0), (c > 0), (c - 1), 1, 1);
        STEP(4 * c + 1, 1, 0, 0, 1, 0, 0, 1, 1);
        STEP(4 * c + 2, 0, 1, 1, 1, 0, 0, 1, 1);
        STEP(4 * c + 3, 1, 0, 2, 1, 0, 0, 1, 1);
    }
    STEP(16, 0, 1, 3, 1, 1, 3, 1, 0);
    STEP(17, 1, 0, 0, 1, 0, 0, 1, 0);
    STEP(18, 0, 1, 1, 1, 0, 0, 0, 0);
#undef STEP

    {
        int cp1 = pendA + pendB;
        int cp2 = cp1 + __shfl_xor(cp1, 32);
        unsigned cnt = ((unsigned)cp2 >> qsh) & 255u;
        cur |= cnt << 16;
        atomicAdd(&lds_cnt[4][lane], (int)cur);
    }
    __syncthreads();

    {
        const int pb = (blockIdx.y << 1) | bx;
        const int k0 = tid >> 6, ch = tid & 63;
        ws[((bz * NCHUNK + k0) * NPB + pb) * CHN + ch] = lds_cnt[k0][ch];
        if (tid < CHN)
            ws[((bz * NCHUNK + 4) * NPB + pb) * CHN + tid] = lds_cnt[4][tid];
    }
}

// ---------------------------------------------------------------------------
// head: block per (t,b), one wave. Reduces 128 byte-packed partials per
// channel, then logits; readout/sr via small atomics (slots zeroed earlier).
// ---------------------------------------------------------------------------
__global__ __launch_bounds__(64) void head_kernel(const int* __restrict__ cw,
                                                  const float* __restrict__ w_head,
                                                  const float* __restrict__ b_head,
                                                  float* __restrict__ out) {
    const int t = blockIdx.x, b = blockIdx.y, ch = threadIdx.x;
    const int k = t >> 2, sh = (t & 3) << 3;
    const int* base = cw + ((b * NCHUNK + k) * NPB) * CHN + ch;

    int cnt = 0;
#pragma unroll 8
    for (int p = 0; p < NPB; ++p) cnt += (base[p * CHN] >> sh) & 255;

    const float s = (float)cnt * (1.f / (HH * WW));
    float acc[NOUT];
#pragma unroll
    for (int o = 0; o < NOUT; ++o) acc[o] = s * w_head[ch * NOUT + o];
    float tt = (float)cnt;
#pragma unroll
    for (int off = 32; off > 0; off >>= 1) {
#pragma unroll
        for (int o = 0; o < NOUT; ++o) acc[o] += __shfl_down(acc[o], off);
        tt += __shfl_down(tt, off);
    }
    if (ch == 0) {
#pragma unroll
        for (int o = 0; o < NOUT; ++o) {
            float lg = acc[o] + b_head[o];
            out[BB * NOUT + (t * BB + b) * NOUT + o] = lg;
            atomicAdd(&out[b * NOUT + o], lg * (1.f / TS));
        }
        atomicAdd(&out[SR_IDX], tt * (1.f / ((float)TS * BB * HH * WW * CHN)));
    }
}

// ---------------------------------------------------------------------------
extern "C" void kernel_launch(void* const* d_in, const int* in_sizes, int n_in,
                              void* d_out, int out_size, void* d_ws, size_t ws_size,
                              hipStream_t stream) {
    (void)in_sizes; (void)n_in; (void)out_size;
    const float* x      = (const float*)d_in[0];
    const float* w_conv = (const float*)d_in[1];
    const float* b_conv = (const float*)d_in[2];
    const float* w_head = (const float*)d_in[3];
    const float* b_head = (const float*)d_in[4];
    float* out = (float*)d_out;

    if (ws_size >= WS_NEED) {
        unsigned* wsf = (unsigned*)d_ws;
        int* cw = (int*)d_ws + CNT_OFF4;
        flow_pack<<<dim3(32, BB), 256, 0, stream>>>(x, wsf);
        lif_fast<<<dim3(2, HH / 2, BB), 256, 0, stream>>>((const char*)d_ws, w_conv, b_conv, cw, out);
        head_kernel<<<dim3(TS, BB), 64, 0, stream>>>(cw, w_head, b_head, out);
    } else {
        int* cw = (int*)d_ws;
        lif_main<<<dim3(2, HH / 2, BB), 256, 0, stream>>>(x, w_conv, b_conv, cw, out);
        head_kernel<<<dim3(TS, BB), 64, 0, stream>>>(cw, w_head, b_head, out);
    }
}

// Round 10
// 141.869 us; speedup vs baseline: 1.2112x; 1.2112x over previous
//
#include <hip/hip_runtime.h>
#include <hip/hip_bf16.h>
#include <hip/hip_fp16.h>

// Problem constants
#define TT   20
#define TS   19          // T-1 steps
#define BB   16
#define HH   128
#define WW   128
#define CINN 2
#define CHN  64
#define NOUT 10
#define BETA 0.9f
#define INVB (1.0f / BETA)

#define NCHUNK 5                              // ceil(19/4) byte-packed t-chunks
#define NPB    128                            // partial blocks per batch
#define SR_IDX (BB*NOUT + TS*BB*NOUT)         // scalar spike-rate slot in out

// ---- packed-flow frame geometry (single f16 plane) ----
// frame[y][pp]: y in 0..128 (row 128 = zeros), pp = px+1 in 0..131
// (pp 0,129,130,131 zeroed -> borderless halo reads). One dword per pixel
// (2 ci x f16).
#define PPD      132
#define ROWB     (PPD*4)                      // 528 B row stride
#define PROWS    129
#define FRAME_B  (PROWS*ROWB)                 // 68,112 B per (b,t) frame
#define FLOW_B   ((size_t)BB*TS*FRAME_B)      // 20,706,048 B
#define SLACK_B  528                          // zeroed tail (x4-load overrun)
#define CNT_OFF4 ((size_t)(FLOW_B + SLACK_B) / 4)
#define CNT_B    ((size_t)BB*NCHUNK*NPB*CHN*4)
#define WS_NEED  (FLOW_B + SLACK_B + CNT_B)   // ~23.3 MB

// ---- round-5 fallback geometry ----
#define LROW  20                              // dwords per staged row (18 + 2 pad)

typedef __attribute__((ext_vector_type(8))) short short8;
typedef _Float16 half8 __attribute__((ext_vector_type(8)));
typedef __attribute__((ext_vector_type(4))) float float4v;
typedef __attribute__((ext_vector_type(4))) int   int4v;
typedef unsigned uint4v_t __attribute__((ext_vector_type(4)));
typedef uint4v_t __attribute__((aligned(4))) uint4vu;   // 4B-aligned vector load
typedef unsigned uint2v_t __attribute__((ext_vector_type(2)));
typedef uint2v_t __attribute__((aligned(4))) uint2vu;   // 4B-aligned vector store

// round-to-nearest-even fp32 -> bf16 bits (fallback path)
__device__ __forceinline__ unsigned rne16(float f) {
    unsigned u = __float_as_uint(f);
    return (u + 0x7fffu + ((u >> 16) & 1u)) >> 16;
}
__device__ __forceinline__ float b2f(unsigned us) { return __uint_as_float(us << 16); }
__device__ __forceinline__ unsigned rndb(float f) {
    unsigned u = __float_as_uint(f);
    return u + 0x7fffu + ((u >> 16) & 1u);
}
__device__ __forceinline__ void pack2(float d0, float d1, unsigned &hi, unsigned &lo) {
    unsigned r0 = rndb(d0), r1 = rndb(d1);
    hi = __builtin_amdgcn_perm(r1, r0, 0x07060302u);
    float e0 = d0 - __uint_as_float(r0 & 0xffff0000u);
    float e1 = d1 - __uint_as_float(r1 & 0xffff0000u);
    lo = __builtin_amdgcn_perm(rndb(e1), rndb(e0), 0x07060302u);
}
// two f32 -> packed f16 pair (ci0 low, ci1 high)
__device__ __forceinline__ unsigned packh2(float a, float b) {
    __half2 h = __floats2half2_rn(a, b);
    return __builtin_bit_cast(unsigned, h);
}

// ---------------------------------------------------------------------------
// flow_pack (f16): t-looped READ-ONCE producer. Block owns 4 rows x 128 px of
// one batch; x[t] carried in registers across the 19-step loop (x read once).
// One f16 plane per frame: ~62 MB total traffic. Borders zeroed in-loop.
// Same iterated ct chain as lif (consistent scaling).
// ---------------------------------------------------------------------------
__global__ __launch_bounds__(256) void flow_pack(const float* __restrict__ x,
                                                 unsigned* __restrict__ wsf) {
    const int bx  = blockIdx.x;               // 0..31 : row-group of 4
    const int b   = blockIdx.y;               // batch
    const int tid = threadIdx.x;
    const int row = (bx << 2) + (tid >> 6);   // 64 threads per row
    const int p0  = (tid & 63) << 1;          // 2 px per thread

    const int TSTR = BB * HH * WW / 2;        // float4s per time slice
    const float4* xr = (const float4*)x + ((b * HH + row) * WW + p0) / 2;
    char* fb = (char*)wsf + (size_t)b * TS * FRAME_B;
    const unsigned off = (unsigned)(row * PPD + p0 + 1) * 4u;

    float4 cur = xr[0];
    float4 nxt = xr[TSTR];
    float ct = 1.f;
#pragma unroll 1
    for (int t = 0; t < TS; ++t) {
        float4 fut = nxt;
        if (t + 2 <= TS) fut = xr[(t + 2) * TSTR];
        float d0 = (nxt.x - cur.x) * ct, d1 = (nxt.y - cur.y) * ct;
        float d2 = (nxt.z - cur.z) * ct, d3 = (nxt.w - cur.w) * ct;
        uint2v_t hv = {packh2(d0, d1), packh2(d2, d3)};
        *(uint2vu*)(fb + off) = hv;
        // border cols pp in {0,129,130,131}, this row
        if ((tid & 63) < 4) {
            int c  = tid & 3;
            int pp = c == 0 ? 0 : 128 + c;
            *(unsigned*)(fb + (row * PPD + pp) * 4) = 0u;
        }
        // zero row 128 (border-y remap target)
        if (bx == 0) {
            if (tid < PPD)
                *(unsigned*)(fb + (128 * PPD + tid) * 4) = 0u;
        }
        cur = nxt; nxt = fut;
        fb += FRAME_B; ct *= INVB;
    }
    if (bx == 0 && b == 0 && tid < PPD)
        *((unsigned*)((char*)wsf + FLOW_B) + tid) = 0u;
}

// ---------------------------------------------------------------------------
// lif_fast (f16, single pass): conv via 8x mfma_f32_16x16x32_f16 per step
// (8 independent depth-1 accumulator chains), NO LDS staging, no validity
// masks (zero-padded frames). Each lane's A-quad = ONE dwordx4 load (dword3
// = dead elem: B k-slots 6,7 are zero; q==3 lanes read row0, B==0).
// Register-double-buffered one frame ahead. W-space LIF via the MFMA
// C-operand; byte-packed deferred counts; zero global atomics.
// ---------------------------------------------------------------------------
__global__ __launch_bounds__(256, 4) void lif_fast(const char* __restrict__ flow,
                                                   const float* __restrict__ w_conv,
                                                   const float* __restrict__ b_conv,
                                                   int* __restrict__ cw,
                                                   float* __restrict__ out) {
    __shared__ int lds_cnt[NCHUNK][CHN];          // 1280 B

    const int tid  = threadIdx.x;
    const int lane = tid & 63;
    const int wv   = __builtin_amdgcn_readfirstlane(tid >> 6);
    const int bx   = blockIdx.x;                 // 0..1 : pixel half
    const int r0   = blockIdx.y << 1;            // first of 2 output rows
    const int bz   = blockIdx.z;                 // batch
    const int q    = lane >> 4;
    const int col  = lane & 15;
    const int x0   = (bx << 6) + (wv << 4);
    const int qsh  = q << 3;

    if (bx == 0 && blockIdx.y == 0 && bz == 0) {
        if (tid < BB * NOUT) out[tid] = 0.f;
        else if (tid == BB * NOUT) out[SR_IDX] = 0.f;
    }
    if (tid < NCHUNK * CHN - 256) ((int*)lds_cnt)[256 + tid] = 0;
    ((int*)lds_cnt)[tid] = 0;
    __syncthreads();

    // per-lane invariant frame offsets (y remapped to zero row at borders)
    const int rq  = (q < 3) ? q : 0;
    const int yA0 = r0 - 1 + rq, yA1 = yA0 + 1;
    const int ym0 = ((unsigned)yA0 < (unsigned)HH) ? yA0 : 128;
    const int ym1 = ((unsigned)yA1 < (unsigned)HH) ? yA1 : 128;
    const int xpx = x0 + col;
    const unsigned offH0 = (unsigned)(ym0 * ROWB + xpx * 4);
    const unsigned offH1 = (unsigned)(ym1 * ROWB + xpx * 4);

    // ---- B fragments (f16): k = q*8+j ; q<3: 6 weight taps ; q==3: zero
    half8 Bf[4];
#pragma unroll
    for (int cg = 0; cg < 4; ++cg) {
        int bi[4] = {0, 0, 0, 0};
        if (q < 3) {
#pragma unroll
            for (int j = 0; j < 6; ++j) {
                float w = w_conv[((q * 3 + (j >> 1)) * 2 + (j & 1)) * CHN + cg * 16 + col];
                unsigned hs = (unsigned)__half_as_ushort(__float2half_rn(w));
                bi[j >> 1] |= (int)(hs << (16 * (j & 1)));
            }
        }
        int4v bv = {bi[0], bi[1], bi[2], bi[3]};
        Bf[cg] = __builtin_bit_cast(half8, bv);
    }

    float nb[4];
#pragma unroll
    for (int cg = 0; cg < 4; ++cg) nb[cg] = -b_conv[cg * 16 + col];

    float4v W0[4], W1[4];
#pragma unroll
    for (int cg = 0; cg < 4; ++cg) {
        W0[cg] = (float4v){0.f, 0.f, 0.f, 0.f};
        W1[cg] = (float4v){0.f, 0.f, 0.f, 0.f};
    }

    float ct = 1.0f, S = 1.0f;
    int pendA = 0, pendB = 0;
    unsigned cur = 0;

    const char* fp = flow + (size_t)bz * TS * FRAME_B;
    // prologue: frame 0 into the E set
    uint4vu eA0 = *(const uint4vu*)(fp + offH0);
    uint4vu eA1 = *(const uint4vu*)(fp + offH1);
    fp += FRAME_B;
    uint4vu oA0, oA1;

#define MFMA16F __builtin_amdgcn_mfma_f32_16x16x32_f16

#define STEP(T_, CA0, CA1, NA0, NA1, DPOS, DODEF, DOFLUSH, CK, DOLOAD) do {     \
    int cp1_ = 0, sh2_ = 0;                                                     \
    if (DODEF) { cp1_ = pendA + pendB; sh2_ = __shfl_xor(cp1_, 32); }           \
    if (DOLOAD) {                                                               \
        NA0 = *(const uint4vu*)(fp + offH0);                                    \
        NA1 = *(const uint4vu*)(fp + offH1);                                    \
        fp += FRAME_B;                                                          \
    }                                                                           \
    float ctn = ct * INVB;                                                      \
    half8 A0 = __builtin_bit_cast(half8, CA0);                                  \
    half8 A1 = __builtin_bit_cast(half8, CA1);                                  \
    __builtin_amdgcn_s_setprio(1);                                              \
    _Pragma("unroll")                                                           \
    for (int cg = 0; cg < 4; ++cg) {                                            \
        W0[cg] = MFMA16F(A0, Bf[cg], W0[cg], 0, 0, 0);                          \
        W1[cg] = MFMA16F(A1, Bf[cg], W1[cg], 0, 0, 0);                          \
    }                                                                           \
    __builtin_amdgcn_s_setprio(0);                                              \
    if (DODEF) {                                                                \
        unsigned cnt_ = ((unsigned)(cp1_ + sh2_) >> qsh) & 255u;                \
        cur |= cnt_ << (8 * (DPOS));                                            \
        if (DOFLUSH) { atomicAdd(&lds_cnt[CK][lane], (int)cur); cur = 0u; }     \
    }                                                                           \
    int cpack = 0;                                                              \
    _Pragma("unroll")                                                           \
    for (int cg = 0; cg < 4; ++cg) {                                            \
        float thr = fmaf(nb[cg], S, ct);                                        \
        float4v w0 = W0[cg], w1 = W1[cg];                                       \
        int c = 0;                                                              \
        _Pragma("unroll")                                                       \
        for (int r = 0; r < 4; ++r) {                                           \
            float v0 = w0[r]; bool s0 = v0 > thr;                               \
            w0[r] = s0 ? (v0 - ct) : v0; c += s0;                               \
            float v1 = w1[r]; bool s1 = v1 > thr;                               \
            w1[r] = s1 ? (v1 - ct) : v1; c += s1;                               \
        }                                                                       \
        W0[cg] = w0; W1[cg] = w1;                                               \
        cpack |= c << (8 * cg);                                                 \
    }                                                                           \
    pendA = cpack;                                                              \
    pendB = __shfl_xor(cpack, 16);                                              \
    ct = ctn; S += ctn;                                                         \
} while (0)

#pragma unroll 1
    for (int c = 0; c < 4; ++c) {                // steps 0..15
        STEP(4 * c + 0, eA0, eA1, oA0, oA1, 3, (c > 0), (c > 0), (c - 1), 1);
        STEP(4 * c + 1, oA0, oA1, eA0, eA1, 0, 1, 0, 0, 1);
        STEP(4 * c + 2, eA0, eA1, oA0, oA1, 1, 1, 0, 0, 1);
        STEP(4 * c + 3, oA0, oA1, eA0, eA1, 2, 1, 0, 0, 1);
    }
    STEP(16, eA0, eA1, oA0, oA1, 3, 1, 1, 3, 1);
    STEP(17, oA0, oA1, eA0, eA1, 0, 1, 0, 0, 1);
    STEP(18, eA0, eA1, oA0, oA1, 1, 1, 0, 0, 0);
#undef STEP
#undef MFMA16F

    // flush step 18's count (byte 2) and chunk 4
    {
        int cp1 = pendA + pendB;
        int cp2 = cp1 + __shfl_xor(cp1, 32);
        unsigned cnt = ((unsigned)cp2 >> qsh) & 255u;
        cur |= cnt << 16;
        atomicAdd(&lds_cnt[4][lane], (int)cur);
    }
    __syncthreads();

    {
        const int pb = (blockIdx.y << 1) | bx;   // 0..127
        const int k0 = tid >> 6, ch = tid & 63;
        cw[((bz * NCHUNK + k0) * NPB + pb) * CHN + ch] = lds_cnt[k0][ch];
        if (tid < CHN)
            cw[((bz * NCHUNK + 4) * NPB + pb) * CHN + tid] = lds_cnt[4][tid];
    }
}

// ---------------------------------------------------------------------------
// Round-5 fallback (small-workspace path): in-loop bf16 pack + LDS staging.
// ---------------------------------------------------------------------------
__global__ __launch_bounds__(256, 4) void lif_main(const float* __restrict__ x,
                                                   const float* __restrict__ w_conv,
                                                   const float* __restrict__ b_conv,
                                                   int* __restrict__ ws,
                                                   float* __restrict__ out) {
    __shared__ unsigned lds[4][2][2][4 * LROW];
    __shared__ int lds_cnt[NCHUNK][CHN];

    const float2* xp2 = (const float2*)x;
    const int FRAME2  = BB * HH * WW;

    const int tid  = threadIdx.x;
    const int lane = tid & 63;
    const int wv   = __builtin_amdgcn_readfirstlane(tid >> 6);
    const int bx   = blockIdx.x;
    const int r0   = blockIdx.y << 1;
    const int bz   = blockIdx.z;
    const int q    = lane >> 4;
    const int col  = lane & 15;
    const int x0   = (bx << 6) + (wv << 4);
    const int qsh  = q << 3;

    if (bx == 0 && blockIdx.y == 0 && bz == 0) {
        if (tid < BB * NOUT) out[tid] = 0.f;
        else if (tid == BB * NOUT) out[SR_IDX] = 0.f;
    }
    if (tid < NCHUNK * CHN - 256) ((int*)lds_cnt)[256 + tid] = 0;
    ((int*)lds_cnt)[tid] = 0;
    __syncthreads();

    const int  row0 = lane / 18, dx0 = lane - row0 * 18;
    const int  y0s  = r0 - 1 + row0;
    const int  px0s = x0 - 1 + dx0;
    const bool val0 = ((unsigned)y0s < (unsigned)HH) && ((unsigned)px0s < (unsigned)WW);
    const int  off0 = val0 ? (y0s * WW + px0s) : 0;
    const int  ls0  = row0 * LROW + dx0;

    const bool act1 = (lane < 8);
    const int  y1s  = r0 + 2;
    const int  px1s = x0 - 1 + 10 + lane;
    const bool val1 = act1 && ((unsigned)y1s < (unsigned)HH) && ((unsigned)px1s < (unsigned)WW);
    const int  off1 = val1 ? (y1s * WW + px1s) : 0;
    const int  ls1  = 3 * LROW + 10 + lane;

    const int rq  = (q < 3) ? q : 0;
    const int rdb = rq * LROW + col;

    short8 Bh[4], Bl[4];
#pragma unroll
    for (int cg = 0; cg < 4; ++cg) {
        int hi_i[4] = {0, 0, 0, 0}, lo_i[4] = {0, 0, 0, 0};
        if (q < 3) {
#pragma unroll
            for (int j = 0; j < 6; ++j) {
                float w = w_conv[((q * 3 + (j >> 1)) * 2 + (j & 1)) * CHN + cg * 16 + col];
                unsigned hs = rne16(w);
                unsigned ls = rne16(w - b2f(hs));
                hi_i[j >> 1] |= (int)(hs << (16 * (j & 1)));
                lo_i[j >> 1] |= (int)(ls << (16 * (j & 1)));
            }
        }
        int4v hv = {hi_i[0], hi_i[1], hi_i[2], hi_i[3]};
        int4v lv = {lo_i[0], lo_i[1], lo_i[2], lo_i[3]};
        Bh[cg] = __builtin_bit_cast(short8, hv);
        Bl[cg] = __builtin_bit_cast(short8, lv);
    }

    float nb[4];
#pragma unroll
    for (int cg = 0; cg < 4; ++cg) nb[cg] = -b_conv[cg * 16 + col];

    float4v W0[4], W1[4];
#pragma unroll
    for (int cg = 0; cg < 4; ++cg) {
        W0[cg] = (float4v){0.f, 0.f, 0.f, 0.f};
        W1[cg] = (float4v){0.f, 0.f, 0.f, 0.f};
    }

    float ct = 1.0f, S = 1.0f;
    int pendA = 0, pendB = 0;
    unsigned cur = 0;

    float2 ra_0 = {0.f, 0.f}, rb_0 = {0.f, 0.f}, rc_0 = {0.f, 0.f};
    float2 ra_1 = {0.f, 0.f}, rb_1 = {0.f, 0.f}, rc_1 = {0.f, 0.f};
    const float2* xb = xp2 + bz * HH * WW;
    if (val0) { rb_0 = xb[off0]; ra_0 = xb[FRAME2 + off0]; rc_0 = xb[2 * FRAME2 + off0]; }
    if (val1) { rb_1 = xb[off1]; ra_1 = xb[FRAME2 + off1]; rc_1 = xb[2 * FRAME2 + off1]; }
    {
        unsigned* hiW = &lds[wv][0][0][0];
        unsigned* loW = &lds[wv][0][1][0];
        {
            float d0 = (ra_0.x - rb_0.x), d1 = (ra_0.y - rb_0.y);
            unsigned hw, lw; pack2(d0, d1, hw, lw);
            hiW[ls0] = hw; loW[ls0] = lw;
        }
        if (act1) {
            float d0 = (ra_1.x - rb_1.x), d1 = (ra_1.y - rb_1.y);
            unsigned hw, lw; pack2(d0, d1, hw, lw);
            hiW[ls1] = hw; loW[ls1] = lw;
        }
        rb_0 = ra_0; ra_0 = rc_0;
        rb_1 = ra_1; ra_1 = rc_1;
        if (val0) rc_0 = xb[3 * FRAME2 + off0];
        if (val1) rc_1 = xb[3 * FRAME2 + off1];
    }
    const float2* xn = xb + 4 * FRAME2;

#define STEP(T_, CURB, NXTB, DPOS, DODEF, DOFLUSH, CK, DOSTAGE, DOPREF) do {    \
    const unsigned* hiR = &lds[wv][CURB][0][0] + rdb;                           \
    const unsigned* loR = &lds[wv][CURB][1][0] + rdb;                           \
    unsigned h0 = hiR[0], h1 = hiR[1], h2 = hiR[2];                             \
    unsigned h3 = hiR[LROW], h4 = hiR[LROW + 1], h5 = hiR[LROW + 2];            \
    unsigned l0 = loR[0], l1 = loR[1], l2 = loR[2];                             \
    unsigned l3 = loR[LROW], l4 = loR[LROW + 1], l5 = loR[LROW + 2];            \
    int cp1_ = 0, sh2_ = 0;                                                     \
    if (DODEF) { cp1_ = pendA + pendB; sh2_ = __shfl_xor(cp1_, 32); }           \
    float ctn = ct * INVB;                                                      \
    if (DOSTAGE) {                                                              \
        unsigned* hiW = &lds[wv][NXTB][0][0];                                   \
        unsigned* loW = &lds[wv][NXTB][1][0];                                   \
        {                                                                       \
            float d0 = (ra_0.x - rb_0.x) * ctn;                                 \
            float d1 = (ra_0.y - rb_0.y) * ctn;                                 \
            unsigned hw, lw; pack2(d0, d1, hw, lw);                             \
            hiW[ls0] = hw; loW[ls0] = lw;                                       \
        }                                                                       \
        if (act1) {                                                             \
            float d0 = (ra_1.x - rb_1.x) * ctn;                                 \
            float d1 = (ra_1.y - rb_1.y) * ctn;                                 \
            unsigned hw, lw; pack2(d0, d1, hw, lw);                             \
            hiW[ls1] = hw; loW[ls1] = lw;                                       \
        }                                                                       \
        rb_0 = ra_0; ra_0 = rc_0;                                               \
        rb_1 = ra_1; ra_1 = rc_1;                                               \
        if (DOPREF) {                                                           \
            if (val0) rc_0 = xn[off0];                                          \
            if (val1) rc_1 = xn[off1];                                          \
            xn += FRAME2;                                                       \
        }                                                                       \
    }                                                                           \
    int4v a0h = {(int)h0, (int)h1, (int)h2, (int)h0};                           \
    int4v a0l = {(int)l0, (int)l1, (int)l2, (int)l0};                           \
    int4v a1h = {(int)h3, (int)h4, (int)h5, (int)h3};                           \
    int4v a1l = {(int)l3, (int)l4, (int)l5, (int)l3};                           \
    short8 A0h = __builtin_bit_cast(short8, a0h);                               \
    short8 A0l = __builtin_bit_cast(short8, a0l);                               \
    short8 A1h = __builtin_bit_cast(short8, a1h);                               \
    short8 A1l = __builtin_bit_cast(short8, a1l);                               \
    __builtin_amdgcn_s_setprio(1);                                              \
    _Pragma("unroll")                                                           \
    for (int cg = 0; cg < 4; ++cg) {                                            \
        W0[cg] = __builtin_amdgcn_mfma_f32_16x16x32_bf16(A0h, Bh[cg], W0[cg], 0, 0, 0); \
        W1[cg] = __builtin_amdgcn_mfma_f32_16x16x32_bf16(A1h, Bh[cg], W1[cg], 0, 0, 0); \
    }                                                                           \
    _Pragma("unroll")                                                           \
    for (int cg = 0; cg < 4; ++cg) {                                            \
        W0[cg] = __builtin_amdgcn_mfma_f32_16x16x32_bf16(A0l, Bh[cg], W0[cg], 0, 0, 0); \
        W1[cg] = __builtin_amdgcn_mfma_f32_16x16x32_bf16(A1l, Bh[cg], W1[cg], 0, 0, 0); \
    }                                                                           \
    _Pragma("unroll")                                                           \
    for (int cg = 0; cg < 4; ++cg) {                                            \
        W0[cg] = __builtin_amdgcn_mfma_f32_16x16x32_bf16(A0h, Bl[cg], W0[cg], 0, 0, 0); \
        W1[cg] = __builtin_amdgcn_mfma_f32_16x16x32_bf16(A1h, Bl[cg], W1[cg], 0, 0, 0); \
    }                                                                           \
    __builtin_amdgcn_s_setprio(0);                                              \
    if (DODEF) {                                                                \
        unsigned cnt_ = ((unsigned)(cp1_ + sh2_) >> qsh) & 255u;                \
        cur |= cnt_ << (8 * (DPOS));                                            \
        if (DOFLUSH) { atomicAdd(&lds_cnt[CK][lane], (int)cur); cur = 0u; }     \
    }                                                                           \
    int cpack = 0;                                                              \
    _Pragma("unroll")                                                           \
    for (int cg = 0; cg < 4; ++cg) {                                            \
        float thr = fmaf(nb[cg], S, ct);                                        \
        float4v w0 = W0[cg], w1 = W1[cg];                                       \
        int c = 0;                                                              \
        _Pragma("unroll")                                                       \
        for (int r = 0; r < 4; ++r) {                                           \
            float v0 = w0[r]; bool s0 = v0 > thr;                               \
            w0[r] = s0 ? (v0 - ct) : v0; c += s0;                               \
            float v1 = w1[r]; bool s1 = v1 > thr;                               \
            w1[r] = s1 ? (v1 - ct) : v1; c += s1;                               \
        }                                                                       \
        W0[cg] = w0; W1[cg] = w1;                                               \
        cpack |= c << (8 * cg);                                                 \
    }                                                                           \
    pendA = cpack;                                                              \
    pendB = __shfl_xor(cpack, 16);                                              \
    ct = ctn; S += ctn;                                                         \
} while (0)

#pragma unroll 1
    for (int c = 0; c < 4; ++c) {
        STEP(4 * c + 0, 0, 1, 3, (c > 0), (c > 0), (c - 1), 1, 1);
        STEP(4 * c + 1, 1, 0, 0, 1, 0, 0, 1, 1);
        STEP(4 * c + 2, 0, 1, 1, 1, 0, 0, 1, 1);
        STEP(4 * c + 3, 1, 0, 2, 1, 0, 0, 1, 1);
    }
    STEP(16, 0, 1, 3, 1, 1, 3, 1, 0);
    STEP(17, 1, 0, 0, 1, 0, 0, 1, 0);
    STEP(18, 0, 1, 1, 1, 0, 0, 0, 0);
#undef STEP

    {
        int cp1 = pendA + pendB;
        int cp2 = cp1 + __shfl_xor(cp1, 32);
        unsigned cnt = ((unsigned)cp2 >> qsh) & 255u;
        cur |= cnt << 16;
        atomicAdd(&lds_cnt[4][lane], (int)cur);
    }
    __syncthreads();

    {
        const int pb = (blockIdx.y << 1) | bx;
        const int k0 = tid >> 6, ch = tid & 63;
        ws[((bz * NCHUNK + k0) * NPB + pb) * CHN + ch] = lds_cnt[k0][ch];
        if (tid < CHN)
            ws[((bz * NCHUNK + 4) * NPB + pb) * CHN + tid] = lds_cnt[4][tid];
    }
}

// ---------------------------------------------------------------------------
// head: block per (t,b), one wave. Reduces 128 byte-packed partials per
// channel, then logits; readout/sr via small atomics (slots zeroed earlier).
// ---------------------------------------------------------------------------
__global__ __launch_bounds__(64) void head_kernel(const int* __restrict__ cw,
                                                  const float* __restrict__ w_head,
                                                  const float* __restrict__ b_head,
                                                  float* __restrict__ out) {
    const int t = blockIdx.x, b = blockIdx.y, ch = threadIdx.x;
    const int k = t >> 2, sh = (t & 3) << 3;
    const int* base = cw + ((b * NCHUNK + k) * NPB) * CHN + ch;

    int cnt = 0;
#pragma unroll 8
    for (int p = 0; p < NPB; ++p) cnt += (base[p * CHN] >> sh) & 255;

    const float s = (float)cnt * (1.f / (HH * WW));
    float acc[NOUT];
#pragma unroll
    for (int o = 0; o < NOUT; ++o) acc[o] = s * w_head[ch * NOUT + o];
    float tt = (float)cnt;
#pragma unroll
    for (int off = 32; off > 0; off >>= 1) {
#pragma unroll
        for (int o = 0; o < NOUT; ++o) acc[o] += __shfl_down(acc[o], off);
        tt += __shfl_down(tt, off);
    }
    if (ch == 0) {
#pragma unroll
        for (int o = 0; o < NOUT; ++o) {
            float lg = acc[o] + b_head[o];
            out[BB * NOUT + (t * BB + b) * NOUT + o] = lg;
            atomicAdd(&out[b * NOUT + o], lg * (1.f / TS));
        }
        atomicAdd(&out[SR_IDX], tt * (1.f / ((float)TS * BB * HH * WW * CHN)));
    }
}

// ---------------------------------------------------------------------------
extern "C" void kernel_launch(void* const* d_in, const int* in_sizes, int n_in,
                              void* d_out, int out_size, void* d_ws, size_t ws_size,
                              hipStream_t stream) {
    (void)in_sizes; (void)n_in; (void)out_size;
    const float* x      = (const float*)d_in[0];
    const float* w_conv = (const float*)d_in[1];
    const float* b_conv = (const float*)d_in[2];
    const float* w_head = (const float*)d_in[3];
    const float* b_head = (const float*)d_in[4];
    float* out = (float*)d_out;

    if (ws_size >= WS_NEED) {
        unsigned* wsf = (unsigned*)d_ws;
        int* cw = (int*)d_ws + CNT_OFF4;
        flow_pack<<<dim3(32, BB), 256, 0, stream>>>(x, wsf);
        lif_fast<<<dim3(2, HH / 2, BB), 256, 0, stream>>>((const char*)d_ws, w_conv, b_conv, cw, out);
        head_kernel<<<dim3(TS, BB), 64, 0, stream>>>(cw, w_head, b_head, out);
    } else {
        int* cw = (int*)d_ws;
        lif_main<<<dim3(2, HH / 2, BB), 256, 0, stream>>>(x, w_conv, b_conv, cw, out);
        head_kernel<<<dim3(TS, BB), 64, 0, stream>>>(cw, w_head, b_head, out);
    }
}